// Round 1
// baseline (91.023 us; speedup 1.0000x reference)
//
#include <hip/hip_runtime.h>
#include <math.h>

// ColorLoss: mean over all (b,m) of min_n ||pred[b,m]-gt[b,n]||_2
// B=4, M=N=8192, D=3. Identity: min dist = sqrt(a2 + min_n(b2[n] - 2*a.b[n]))
// -> inner loop is 3 fma + 1 min per distance. VALU-bound fp32 problem.

constexpr int B    = 4;
constexpr int M    = 8192;
constexpr int N    = 8192;
constexpr int BM   = B * M;        // 32768 query points
constexpr int TPB  = 256;          // threads per block
constexpr int RPT  = 8;            // query points per thread (register-blocked)
constexpr int PPB  = TPB * RPT;    // 2048 points per block
constexpr int MBLK = M / PPB;      // 4 point-blocks per batch
constexpr int TILE = 1024;         // gt float4s staged per LDS round (16 KiB)

// grid = B * MBLK * S, S = N/NSEG segments of the gt set.
// FINAL=true (S==1): finish sqrt + block-sum into partials directly.
template <int NSEG, bool FINAL>
__global__ __launch_bounds__(TPB)
void k_min(const float* __restrict__ pred, const float* __restrict__ gt,
           float* __restrict__ ws_min, float* __restrict__ partials)
{
  constexpr int S  = N / NSEG;
  constexpr int CH = (TILE < NSEG ? TILE : NSEG);
  const int bid = blockIdx.x;
  const int seg = bid % S;
  const int mb  = (bid / S) % MBLK;
  const int b   = bid / (S * MBLK);
  const int t   = threadIdx.x;

  __shared__ float4 tile[CH];

  // per-thread query coefficients: s(n) = b2[n] + (-2ax)*bx + (-2ay)*by + (-2az)*bz
  float cx[RPT], cy[RPT], cz[RPT], mins[RPT];
  const int mbase = mb * PPB + t;
#pragma unroll
  for (int r = 0; r < RPT; ++r) {
    const float* a = pred + ((size_t)b * M + (mbase + r * TPB)) * 3;
    cx[r] = -2.0f * a[0];
    cy[r] = -2.0f * a[1];
    cz[r] = -2.0f * a[2];
    mins[r] = 3.0e38f;
  }

  const int nbase = seg * NSEG;
  for (int n0 = 0; n0 < NSEG; n0 += CH) {
    __syncthreads();
    // stage gt tile as (x, y, z, |g|^2)
    for (int i = t; i < CH; i += TPB) {
      const float* g = gt + ((size_t)b * N + (nbase + n0 + i)) * 3;
      float gx = g[0], gy = g[1], gz = g[2];
      tile[i] = make_float4(gx, gy, gz, fmaf(gx, gx, fmaf(gy, gy, gz * gz)));
    }
    __syncthreads();
#pragma unroll 4
    for (int n = 0; n < CH; ++n) {
      const float4 g = tile[n];   // broadcast ds_read_b128 (all lanes same addr)
#pragma unroll
      for (int r = 0; r < RPT; ++r) {
        float s = fmaf(cx[r], g.x, fmaf(cy[r], g.y, fmaf(cz[r], g.z, g.w)));
        mins[r] = fminf(mins[r], s);
      }
    }
  }

  if (!FINAL) {
    // layout [seg][b*M + m]: coalesced store here, coalesced load in k_combine
    float* dst = ws_min + (size_t)seg * BM + (size_t)b * M + mbase;
#pragma unroll
    for (int r = 0; r < RPT; ++r) dst[r * TPB] = mins[r];
  } else {
    float sum = 0.0f;
#pragma unroll
    for (int r = 0; r < RPT; ++r) {
      const float* a = pred + ((size_t)b * M + (mbase + r * TPB)) * 3;
      float a2 = fmaf(a[0], a[0], fmaf(a[1], a[1], a[2] * a[2]));
      sum += sqrtf(fmaxf(a2 + mins[r], 0.0f));
    }
    for (int off = 32; off > 0; off >>= 1) sum += __shfl_down(sum, off, 64);
    __shared__ float wsum[TPB / 64];
    if ((t & 63) == 0) wsum[t >> 6] = sum;
    __syncthreads();
    if (t == 0) {
      float s2 = 0.0f;
#pragma unroll
      for (int w = 0; w < TPB / 64; ++w) s2 += wsum[w];
      partials[bid] = s2;
    }
  }
}

// cross-segment min + sqrt + block partial sum. grid = BM/TPB = 128 blocks.
__global__ __launch_bounds__(TPB)
void k_combine(const float* __restrict__ pred, const float* __restrict__ ws_min,
               float* __restrict__ partials, int S)
{
  const int p = blockIdx.x * TPB + threadIdx.x;   // global point index
  float v = 3.0e38f;
#pragma unroll 8
  for (int s = 0; s < S; ++s) v = fminf(v, ws_min[(size_t)s * BM + p]);
  const float* a = pred + (size_t)p * 3;
  float a2  = fmaf(a[0], a[0], fmaf(a[1], a[1], a[2] * a[2]));
  float sum = sqrtf(fmaxf(a2 + v, 0.0f));
  for (int off = 32; off > 0; off >>= 1) sum += __shfl_down(sum, off, 64);
  __shared__ float wsum[TPB / 64];
  if ((threadIdx.x & 63) == 0) wsum[threadIdx.x >> 6] = sum;
  __syncthreads();
  if (threadIdx.x == 0) {
    float s2 = 0.0f;
#pragma unroll
    for (int w = 0; w < TPB / 64; ++w) s2 += wsum[w];
    partials[blockIdx.x] = s2;
  }
}

// final: sum partials (double), divide by BM, write scalar. 1 block.
__global__ __launch_bounds__(TPB)
void k_final(const float* __restrict__ partials, int n, float* __restrict__ out)
{
  double s = 0.0;
  for (int i = threadIdx.x; i < n; i += TPB) s += (double)partials[i];
  for (int off = 32; off > 0; off >>= 1) s += __shfl_down(s, off, 64);
  __shared__ double sh[TPB / 64];
  if ((threadIdx.x & 63) == 0) sh[threadIdx.x >> 6] = s;
  __syncthreads();
  if (threadIdx.x == 0) {
    double tot = 0.0;
#pragma unroll
    for (int w = 0; w < TPB / 64; ++w) tot += sh[w];
    out[0] = (float)(tot / (double)BM);   // LOSS_WEIGHT = 1.0
  }
}

extern "C" void kernel_launch(void* const* d_in, const int* in_sizes, int n_in,
                              void* d_out, int out_size, void* d_ws, size_t ws_size,
                              hipStream_t stream)
{
  const float* pred = (const float*)d_in[0];
  const float* gt   = (const float*)d_in[1];
  float* out = (float*)d_out;

  // largest segment count whose per-(point,seg) min buffer fits in d_ws
  int S = 64;
  while (S > 1 && (size_t)S * BM * sizeof(float) + 1024 > ws_size) S >>= 1;

  if (S > 1) {
    float* ws_min   = (float*)d_ws;
    float* partials = (float*)((char*)d_ws + (size_t)S * BM * sizeof(float));
    const dim3 grid(B * MBLK * S), blk(TPB);
    switch (S) {
      case 64: k_min<N / 64, false><<<grid, blk, 0, stream>>>(pred, gt, ws_min, nullptr); break;
      case 32: k_min<N / 32, false><<<grid, blk, 0, stream>>>(pred, gt, ws_min, nullptr); break;
      case 16: k_min<N / 16, false><<<grid, blk, 0, stream>>>(pred, gt, ws_min, nullptr); break;
      case 8:  k_min<N / 8,  false><<<grid, blk, 0, stream>>>(pred, gt, ws_min, nullptr); break;
      case 4:  k_min<N / 4,  false><<<grid, blk, 0, stream>>>(pred, gt, ws_min, nullptr); break;
      case 2:  k_min<N / 2,  false><<<grid, blk, 0, stream>>>(pred, gt, ws_min, nullptr); break;
    }
    k_combine<<<dim3(BM / TPB), dim3(TPB), 0, stream>>>(pred, ws_min, partials, S);
    k_final<<<dim3(1), dim3(TPB), 0, stream>>>(partials, BM / TPB, out);
  } else {
    // tiny-workspace fallback: finish per-point result in one pass
    float* partials = (float*)d_ws;
    k_min<N, true><<<dim3(B * MBLK), dim3(TPB), 0, stream>>>(pred, gt, nullptr, partials);
    k_final<<<dim3(1), dim3(TPB), 0, stream>>>(partials, B * MBLK, out);
  }
}

// Round 2
// 89.270 us; speedup vs baseline: 1.0196x; 1.0196x over previous
//
#include <hip/hip_runtime.h>
#include <math.h>

// ColorLoss: mean over all (b,m) of min_n ||pred[b,m]-gt[b,n]||_2
// B=4, M=N=8192, D=3. min dist = sqrt(a2 + min_n(b2[n] - 2*a.b[n]))
// Inner loop: 2 gt points/iter -> 6 v_fma_f32 + 1 v_min3_f32 = 3.5 instr/dist.

constexpr int B    = 4;
constexpr int M    = 8192;
constexpr int N    = 8192;
constexpr int BM   = B * M;        // 32768 query points
constexpr int TPB  = 256;
constexpr int RPT  = 8;            // query points per thread
constexpr int PPB  = TPB * RPT;    // 2048 points per block
constexpr int MBLK = M / PPB;      // 4 point-blocks per batch
constexpr int TILE = 1024;         // max gt float4s staged per LDS round

// grid = B * MBLK * S, S = N/NSEG segments. FINAL=true (S==1): finish in-kernel.
template <int NSEG, bool FINAL>
__global__ __launch_bounds__(TPB)
void k_min(const float* __restrict__ pred, const float* __restrict__ gt,
           float* __restrict__ ws_min, float* __restrict__ out)
{
  constexpr int S  = N / NSEG;
  constexpr int CH = (TILE < NSEG ? TILE : NSEG);
  const int bid = blockIdx.x;
  const int seg = bid % S;
  const int mb  = (bid / S) % MBLK;
  const int b   = bid / (S * MBLK);
  const int t   = threadIdx.x;

  __shared__ float4 tile[CH];

  float cx[RPT], cy[RPT], cz[RPT], mn[RPT];
  const int mbase = mb * PPB + t;
#pragma unroll
  for (int r = 0; r < RPT; ++r) {
    const float* a = pred + ((size_t)b * M + (mbase + r * TPB)) * 3;
    cx[r] = -2.0f * a[0];
    cy[r] = -2.0f * a[1];
    cz[r] = -2.0f * a[2];
    mn[r] = 3.0e38f;
  }

  const int nbase = seg * NSEG;
  for (int n0 = 0; n0 < NSEG; n0 += CH) {
    __syncthreads();
    for (int i = t; i < CH; i += TPB) {
      const float* g = gt + ((size_t)b * N + (nbase + n0 + i)) * 3;
      float gx = g[0], gy = g[1], gz = g[2];
      tile[i] = make_float4(gx, gy, gz, fmaf(gx, gx, fmaf(gy, gy, gz * gz)));
    }
    __syncthreads();
#pragma unroll 2
    for (int n = 0; n < CH; n += 2) {
      const float4 g0 = tile[n];       // broadcast ds_read_b128
      const float4 g1 = tile[n + 1];
#pragma unroll
      for (int r = 0; r < RPT; ++r) {
        float s0 = fmaf(cx[r], g0.x, fmaf(cy[r], g0.y, fmaf(cz[r], g0.z, g0.w)));
        float s1 = fmaf(cx[r], g1.x, fmaf(cy[r], g1.y, fmaf(cz[r], g1.z, g1.w)));
        mn[r] = fminf(fminf(s0, s1), mn[r]);   // -> v_min3_f32
      }
    }
  }

  if (!FINAL) {
    // layout [seg][b*M + m]: coalesced store, coalesced load in k_combine
    float* dst = ws_min + (size_t)seg * BM + (size_t)b * M + mbase;
#pragma unroll
    for (int r = 0; r < RPT; ++r) dst[r * TPB] = mn[r];
  } else {
    float sum = 0.0f;
#pragma unroll
    for (int r = 0; r < RPT; ++r) {
      const float* a = pred + ((size_t)b * M + (mbase + r * TPB)) * 3;
      float a2 = fmaf(a[0], a[0], fmaf(a[1], a[1], a[2] * a[2]));
      sum += sqrtf(fmaxf(a2 + mn[r], 0.0f)) * (1.0f / BM);
    }
    for (int off = 32; off > 0; off >>= 1) sum += __shfl_down(sum, off, 64);
    __shared__ float wsum[TPB / 64];
    if ((t & 63) == 0) wsum[t >> 6] = sum;
    __syncthreads();
    if (t == 0) {
      float s2 = 0.0f;
#pragma unroll
      for (int w = 0; w < TPB / 64; ++w) s2 += wsum[w];
      atomicAdd(out, s2);
    }
  }
}

// cross-segment min + sqrt + block sum + atomicAdd(out). grid = BM/TPB = 128.
template <int S>
__global__ __launch_bounds__(TPB)
void k_combine(const float* __restrict__ pred, const float* __restrict__ ws_min,
               float* __restrict__ out)
{
  const int p = blockIdx.x * TPB + threadIdx.x;
  float v0 = 3.0e38f, v1 = 3.0e38f, v2 = 3.0e38f, v3 = 3.0e38f;
#pragma unroll
  for (int s = 0; s < S; s += 4) {       // 4 independent min chains
    v0 = fminf(v0, ws_min[(size_t)(s + 0) * BM + p]);
    v1 = fminf(v1, ws_min[(size_t)(s + 1) * BM + p]);
    v2 = fminf(v2, ws_min[(size_t)(s + 2) * BM + p]);
    v3 = fminf(v3, ws_min[(size_t)(s + 3) * BM + p]);
  }
  float v = fminf(fminf(v0, v1), fminf(v2, v3));
  const float* a = pred + (size_t)p * 3;
  float a2  = fmaf(a[0], a[0], fmaf(a[1], a[1], a[2] * a[2]));
  float sum = sqrtf(fmaxf(a2 + v, 0.0f)) * (1.0f / BM);
  for (int off = 32; off > 0; off >>= 1) sum += __shfl_down(sum, off, 64);
  __shared__ float wsum[TPB / 64];
  if ((threadIdx.x & 63) == 0) wsum[threadIdx.x >> 6] = sum;
  __syncthreads();
  if (threadIdx.x == 0) {
    float s2 = 0.0f;
#pragma unroll
    for (int w = 0; w < TPB / 64; ++w) s2 += wsum[w];
    atomicAdd(out, s2);
  }
}

extern "C" void kernel_launch(void* const* d_in, const int* in_sizes, int n_in,
                              void* d_out, int out_size, void* d_ws, size_t ws_size,
                              hipStream_t stream)
{
  const float* pred = (const float*)d_in[0];
  const float* gt   = (const float*)d_in[1];
  float* out = (float*)d_out;

  // d_out is poisoned 0xAA before every timed call; zero it for the atomics.
  hipMemsetAsync(out, 0, sizeof(float), stream);

  int S = 64;
  while (S > 1 && (size_t)S * BM * sizeof(float) > ws_size) S >>= 1;

  if (S >= 4) {
    float* ws_min = (float*)d_ws;
    const dim3 grid(B * MBLK * S), blk(TPB);
    switch (S) {
      case 64:
        k_min<N / 64, false><<<grid, blk, 0, stream>>>(pred, gt, ws_min, nullptr);
        k_combine<64><<<dim3(BM / TPB), blk, 0, stream>>>(pred, ws_min, out);
        break;
      case 32:
        k_min<N / 32, false><<<grid, blk, 0, stream>>>(pred, gt, ws_min, nullptr);
        k_combine<32><<<dim3(BM / TPB), blk, 0, stream>>>(pred, ws_min, out);
        break;
      case 16:
        k_min<N / 16, false><<<grid, blk, 0, stream>>>(pred, gt, ws_min, nullptr);
        k_combine<16><<<dim3(BM / TPB), blk, 0, stream>>>(pred, ws_min, out);
        break;
      case 8:
        k_min<N / 8, false><<<grid, blk, 0, stream>>>(pred, gt, ws_min, nullptr);
        k_combine<8><<<dim3(BM / TPB), blk, 0, stream>>>(pred, ws_min, out);
        break;
      case 4:
        k_min<N / 4, false><<<grid, blk, 0, stream>>>(pred, gt, ws_min, nullptr);
        k_combine<4><<<dim3(BM / TPB), blk, 0, stream>>>(pred, ws_min, out);
        break;
    }
  } else {
    // tiny-workspace fallback: single pass, atomic accumulate
    k_min<N, true><<<dim3(B * MBLK), dim3(TPB), 0, stream>>>(pred, gt, nullptr, out);
  }
}